// Round 1
// baseline (771.399 us; speedup 1.0000x reference)
//
#include <hip/hip_runtime.h>
#include <hip/hip_bf16.h>

// Problem constants: B=8, DIM=256, HEADS=8, HD=32, WS=8, TOPK=4, H=W=64,
// gh=gw=8, R=64, T=64, BH=64, pixels/batch=4096.
#define ATT_SCALE 0.17677669529663687f

__device__ __forceinline__ float bflo(unsigned u){ union{unsigned i;float f;}x; x.i=u<<16; return x.f; }
__device__ __forceinline__ float bfhi(unsigned u){ union{unsigned i;float f;}x; x.i=u&0xffff0000u; return x.f; }
__device__ __forceinline__ unsigned pack_bf2(float a, float b){
  __hip_bfloat16 ha = __float2bfloat16(a), hb = __float2bfloat16(b);
  unsigned short ua = *reinterpret_cast<unsigned short*>(&ha);
  unsigned short ub = *reinterpret_cast<unsigned short*>(&hb);
  return (unsigned)ua | ((unsigned)ub << 16);
}

// 64x64 tile GEMM micro-kernel: 4x4 per thread, K=64 LDS tiles, float4 reads.
__device__ __forceinline__ void gemm_micro(const float (* __restrict__ Wt)[68],
                                           const float (* __restrict__ Xt)[68],
                                           int to, int tp, float acc[4][4]) {
  #pragma unroll
  for (int kk = 0; kk < 64; kk += 4) {
    float4 av0 = *(const float4*)&Wt[to*4+0][kk];
    float4 av1 = *(const float4*)&Wt[to*4+1][kk];
    float4 av2 = *(const float4*)&Wt[to*4+2][kk];
    float4 av3 = *(const float4*)&Wt[to*4+3][kk];
    float4 bv0 = *(const float4*)&Xt[kk+0][tp*4];
    float4 bv1 = *(const float4*)&Xt[kk+1][tp*4];
    float4 bv2 = *(const float4*)&Xt[kk+2][tp*4];
    float4 bv3 = *(const float4*)&Xt[kk+3][tp*4];
    acc[0][0] += av0.x*bv0.x + av0.y*bv1.x + av0.z*bv2.x + av0.w*bv3.x;
    acc[0][1] += av0.x*bv0.y + av0.y*bv1.y + av0.z*bv2.y + av0.w*bv3.y;
    acc[0][2] += av0.x*bv0.z + av0.y*bv1.z + av0.z*bv2.z + av0.w*bv3.z;
    acc[0][3] += av0.x*bv0.w + av0.y*bv1.w + av0.z*bv2.w + av0.w*bv3.w;
    acc[1][0] += av1.x*bv0.x + av1.y*bv1.x + av1.z*bv2.x + av1.w*bv3.x;
    acc[1][1] += av1.x*bv0.y + av1.y*bv1.y + av1.z*bv2.y + av1.w*bv3.y;
    acc[1][2] += av1.x*bv0.z + av1.y*bv1.z + av1.z*bv2.z + av1.w*bv3.z;
    acc[1][3] += av1.x*bv0.w + av1.y*bv1.w + av1.z*bv2.w + av1.w*bv3.w;
    acc[2][0] += av2.x*bv0.x + av2.y*bv1.x + av2.z*bv2.x + av2.w*bv3.x;
    acc[2][1] += av2.x*bv0.y + av2.y*bv1.y + av2.z*bv2.y + av2.w*bv3.y;
    acc[2][2] += av2.x*bv0.z + av2.y*bv1.z + av2.z*bv2.z + av2.w*bv3.z;
    acc[2][3] += av2.x*bv0.w + av2.y*bv1.w + av2.z*bv2.w + av2.w*bv3.w;
    acc[3][0] += av3.x*bv0.x + av3.y*bv1.x + av3.z*bv2.x + av3.w*bv3.x;
    acc[3][1] += av3.x*bv0.y + av3.y*bv1.y + av3.z*bv2.y + av3.w*bv3.y;
    acc[3][2] += av3.x*bv0.z + av3.y*bv1.z + av3.z*bv2.z + av3.w*bv3.z;
    acc[3][3] += av3.x*bv0.w + av3.y*bv1.w + av3.z*bv2.w + av3.w*bv3.w;
  }
}

// Kernel 1: qkv = w_qkv @ x + b, scattered into window layout [BH][R][T][HD] bf16.
__global__ __launch_bounds__(256) void k_qkv(
    const float* __restrict__ x, const float* __restrict__ w_qkv,
    const float* __restrict__ b_qkv, __hip_bfloat16* __restrict__ qw,
    __hip_bfloat16* __restrict__ kw, __hip_bfloat16* __restrict__ vw) {
  __shared__ float Wt[64][68];
  __shared__ float Xt[64][68];
  const int tid = threadIdx.x;
  const int o0 = blockIdx.x << 6;        // 0..704, 64 out-channels per tile
  const int ptile = blockIdx.y;          // 0..511 (b*64 + image-row)
  const int b = ptile >> 6;
  const int p0 = (ptile & 63) << 6;      // one full image row (h fixed, w=0..63)
  const int to = tid >> 4, tp = tid & 15;
  float acc[4][4];
  #pragma unroll
  for (int i = 0; i < 4; ++i)
    #pragma unroll
    for (int j = 0; j < 4; ++j) acc[i][j] = 0.f;

  for (int k0 = 0; k0 < 256; k0 += 64) {
    __syncthreads();
    #pragma unroll
    for (int i = 0; i < 4; ++i) {
      int vi = i*256 + tid;
      int row = vi >> 4, c4 = (vi & 15) << 2;
      *(float4*)&Wt[row][c4] = *(const float4*)&w_qkv[(o0+row)*256 + k0 + c4];
      *(float4*)&Xt[row][c4] = *(const float4*)&x[(b*256 + k0 + row)*4096 + p0 + c4];
    }
    __syncthreads();
    gemm_micro(Wt, Xt, to, tp, acc);
  }

  __syncthreads();
  #pragma unroll
  for (int i = 0; i < 4; ++i) {
    float bias = b_qkv[o0 + to*4 + i];
    #pragma unroll
    for (int j = 0; j < 4; ++j) Wt[to*4+i][tp*4+j] = acc[i][j] + bias;
  }
  __syncthreads();

  const int hrow = ptile & 63;
  const int rbase = (hrow >> 3) << 3, tbase = (hrow & 7) << 3;
  const int sel = o0 >> 8;                       // 0=q 1=k 2=v (tiles don't straddle)
  __hip_bfloat16* outbuf = sel == 0 ? qw : (sel == 1 ? kw : vw);
  const int headbase = (o0 & 255) >> 5;          // 2 heads per 64-channel tile
  #pragma unroll
  for (int ii = 0; ii < 2; ++ii) {
    int vi = ii*256 + tid;
    int d8 = (vi & 3) << 3;
    int p  = (vi >> 2) & 63;
    int hh2 = vi >> 8;
    int ol = hh2*32 + d8;
    int rr = rbase + (p >> 3), tt = tbase + (p & 7);
    int bh = b*8 + headbase + hh2;
    uint4 u;
    u.x = pack_bf2(Wt[ol+0][p], Wt[ol+1][p]);
    u.y = pack_bf2(Wt[ol+2][p], Wt[ol+3][p]);
    u.z = pack_bf2(Wt[ol+4][p], Wt[ol+5][p]);
    u.w = pack_bf2(Wt[ol+6][p], Wt[ol+7][p]);
    *(uint4*)(outbuf + (((bh*64 + rr)*64 + tt)*32 + d8)) = u;
  }
}

// Kernel 2a: per-(b,c) window means of x  -> xmean[b][c][r]  (fp32, exact-ish).
__global__ __launch_bounds__(256) void k_xmean(const float* __restrict__ x,
                                               float* __restrict__ xmean) {
  __shared__ float part[64][8];
  const int bc = blockIdx.x;               // 0..2047
  const int tid = threadIdx.x;
  const int h = tid >> 2, qq = tid & 3;
  const float* xp = x + bc*4096 + h*64 + qq*16;
  float s0 = 0.f, s1 = 0.f;
  #pragma unroll
  for (int j = 0; j < 8; ++j) { s0 += xp[j]; s1 += xp[8+j]; }
  part[h][qq*2]   = s0;
  part[h][qq*2+1] = s1;
  __syncthreads();
  if (tid < 64) {
    int rh = tid >> 3, wc = tid & 7;
    float s = 0.f;
    #pragma unroll
    for (int j = 0; j < 8; ++j) s += part[rh*8+j][wc];
    xmean[bc*64 + tid] = s * (1.0f/64.0f);
  }
}

// Kernel 2b: region routing. q_r = W_q * xmean + b (mean commutes with 1x1 conv),
// attn_r = q_r k_r^T, top-4 per row. Entirely fp32 -> matches np ranking.
__global__ __launch_bounds__(256) void k_route(const float* __restrict__ xmean,
                                               const float* __restrict__ w_qkv,
                                               const float* __restrict__ b_qkv,
                                               int* __restrict__ topk) {
  __shared__ float xm[128][64];    // 32 KB, reused as attn_r later
  __shared__ float qr[64][33];
  __shared__ float kr[64][33];
  const int bh = blockIdx.x, b = bh >> 3, head = bh & 7;
  const int tid = threadIdx.x;
  const int d = tid & 31, r0 = tid >> 5;     // r0 in 0..7
  float qacc[8], kacc[8];
  const float bq = b_qkv[head*32 + d], bk = b_qkv[256 + head*32 + d];
  #pragma unroll
  for (int i = 0; i < 8; ++i) { qacc[i] = bq; kacc[i] = bk; }

  for (int c0 = 0; c0 < 256; c0 += 128) {
    __syncthreads();
    #pragma unroll
    for (int i = 0; i < 32; ++i) {
      int idx = i*256 + tid;
      int row = idx >> 6, col = idx & 63;
      xm[row][col] = xmean[(b*256 + c0 + row)*64 + col];
    }
    __syncthreads();
    const float* wqp = w_qkv + (head*32 + d)*256 + c0;
    const float* wkp = w_qkv + (256 + head*32 + d)*256 + c0;
    for (int c = 0; c < 128; ++c) {
      float wq = wqp[c], wk = wkp[c];
      #pragma unroll
      for (int i = 0; i < 8; ++i) {
        float xv = xm[c][r0 + 8*i];
        qacc[i] += wq * xv;
        kacc[i] += wk * xv;
      }
    }
  }
  #pragma unroll
  for (int i = 0; i < 8; ++i) { qr[r0+8*i][d] = qacc[i]; kr[r0+8*i][d] = kacc[i]; }
  __syncthreads();

  float* ar = &xm[0][0];          // [64*64]
  for (int item = tid; item < 4096; item += 256) {
    int i = item >> 6, j = item & 63;
    float s = 0.f;
    #pragma unroll
    for (int dd = 0; dd < 32; ++dd) s += qr[i][dd]*kr[j][dd];
    ar[i*64 + j] = s;             // scale omitted: monotonic for ranking
  }
  __syncthreads();
  if (tid < 64) {
    for (int kk = 0; kk < 4; ++kk) {
      float best = -3e38f; int bj = 0;
      for (int j = 0; j < 64; ++j) {
        float v = ar[tid*64 + j];
        if (v > best) { best = v; bj = j; }   // strict > keeps lowest index on ties
      }
      ar[tid*64 + bj] = -3e38f;
      topk[(bh*64 + tid)*4 + kk] = bj;
    }
  }
}

// Kernel 3: token attention. One block per (bh, region). 4 waves x 16 q-tokens;
// 4 lanes per q-row split the 64 keys of each window; online softmax; shfl merge.
__global__ __launch_bounds__(256) void k_attn(const __hip_bfloat16* __restrict__ qw,
                                              const __hip_bfloat16* __restrict__ kw,
                                              const __hip_bfloat16* __restrict__ vw,
                                              const int* __restrict__ topk,
                                              __hip_bfloat16* __restrict__ ow) {
  __shared__ float ks[64][36];   // pad 36: float4-aligned + conflict-free for s=4*sj+g
  __shared__ float vs[64][36];
  const int blk = blockIdx.x;
  const int bh = blk >> 6, rr = blk & 63;
  const int tid = threadIdx.x;
  const int wave = tid >> 6, lane = tid & 63;
  const int tokl = lane & 15, g = lane >> 4;
  const int tok = wave*16 + tokl;

  float qreg[32];
  {
    const uint4* qp4 = (const uint4*)(qw + ((bh*64 + rr)*64 + tok)*32);
    #pragma unroll
    for (int q = 0; q < 4; ++q) {
      uint4 u = qp4[q];
      qreg[8*q+0]=bflo(u.x); qreg[8*q+1]=bfhi(u.x);
      qreg[8*q+2]=bflo(u.y); qreg[8*q+3]=bfhi(u.y);
      qreg[8*q+4]=bflo(u.z); qreg[8*q+5]=bfhi(u.z);
      qreg[8*q+6]=bflo(u.w); qreg[8*q+7]=bfhi(u.w);
    }
  }
  int idx4[4];
  #pragma unroll
  for (int k2 = 0; k2 < 4; ++k2) idx4[k2] = topk[(bh*64 + rr)*4 + k2];

  float m = -3e38f, ssum = 0.f;
  float o[32];
  #pragma unroll
  for (int dd = 0; dd < 32; ++dd) o[dd] = 0.f;

  for (int win = 0; win < 4; ++win) {
    const int widx = idx4[win];
    __syncthreads();
    {
      const uint4* kp4 = (const uint4*)(kw + ((bh*64 + widx)*64)*32);
      const uint4* vp4 = (const uint4*)(vw + ((bh*64 + widx)*64)*32);
      uint4 kv = kp4[tid], vv = vp4[tid];
      int t2 = tid >> 2, d2 = (tid & 3) << 3;
      *(float4*)&ks[t2][d2]   = make_float4(bflo(kv.x),bfhi(kv.x),bflo(kv.y),bfhi(kv.y));
      *(float4*)&ks[t2][d2+4] = make_float4(bflo(kv.z),bfhi(kv.z),bflo(kv.w),bfhi(kv.w));
      *(float4*)&vs[t2][d2]   = make_float4(bflo(vv.x),bfhi(vv.x),bflo(vv.y),bfhi(vv.y));
      *(float4*)&vs[t2][d2+4] = make_float4(bflo(vv.z),bfhi(vv.z),bflo(vv.w),bfhi(vv.w));
    }
    __syncthreads();
    for (int sj = 0; sj < 16; ++sj) {
      const int s = (sj << 2) | g;
      float dot = 0.f;
      #pragma unroll
      for (int q = 0; q < 8; ++q) {
        float4 kv = ((const float4*)&ks[s][0])[q];
        dot += qreg[4*q+0]*kv.x + qreg[4*q+1]*kv.y + qreg[4*q+2]*kv.z + qreg[4*q+3]*kv.w;
      }
      dot *= ATT_SCALE;
      float mnew = fmaxf(m, dot);
      float corr = __expf(m - mnew);
      float p = __expf(dot - mnew);
      ssum = ssum*corr + p;
      #pragma unroll
      for (int q = 0; q < 8; ++q) {
        float4 vv = ((const float4*)&vs[s][0])[q];
        o[4*q+0] = o[4*q+0]*corr + p*vv.x;
        o[4*q+1] = o[4*q+1]*corr + p*vv.y;
        o[4*q+2] = o[4*q+2]*corr + p*vv.z;
        o[4*q+3] = o[4*q+3]*corr + p*vv.w;
      }
      m = mnew;
    }
  }

  // merge the 4 partial states (lanes l, l^16, l^32, l^48)
  #pragma unroll
  for (int mask = 16; mask <= 32; mask <<= 1) {
    float m2 = __shfl_xor(m, mask);
    float s2 = __shfl_xor(ssum, mask);
    float mn = fmaxf(m, m2);
    float c1 = __expf(m - mn), c2 = __expf(m2 - mn);
    ssum = ssum*c1 + s2*c2;
    #pragma unroll
    for (int dd = 0; dd < 32; ++dd) {
      float o2 = __shfl_xor(o[dd], mask);
      o[dd] = o[dd]*c1 + o2*c2;
    }
    m = mn;
  }
  if (g == 0) {
    float inv = 1.0f / ssum;
    __hip_bfloat16* op = ow + ((bh*64 + rr)*64 + tok)*32;
    #pragma unroll
    for (int q = 0; q < 4; ++q) {
      uint4 u;
      u.x = pack_bf2(o[8*q+0]*inv, o[8*q+1]*inv);
      u.y = pack_bf2(o[8*q+2]*inv, o[8*q+3]*inv);
      u.z = pack_bf2(o[8*q+4]*inv, o[8*q+5]*inv);
      u.w = pack_bf2(o[8*q+6]*inv, o[8*q+7]*inv);
      *(uint4*)(op + 8*q) = u;
    }
  }
}

// Kernel 4: out = w_proj @ out_w + b_proj, window layout gathered back to NCHW fp32.
__global__ __launch_bounds__(256) void k_proj(const __hip_bfloat16* __restrict__ ow,
                                              const float* __restrict__ w_proj,
                                              const float* __restrict__ b_proj,
                                              float* __restrict__ out) {
  __shared__ float Wt[64][68];
  __shared__ float Xt[64][68];
  const int tid = threadIdx.x;
  const int o0 = blockIdx.x << 6;        // 0..192
  const int ptile = blockIdx.y;          // 0..511
  const int b = ptile >> 6;
  const int p0 = (ptile & 63) << 6;
  const int to = tid >> 4, tp = tid & 15;
  const int hrow = ptile & 63;
  const int rbase = (hrow >> 3) << 3, tbase = (hrow & 7) << 3;
  float acc[4][4];
  #pragma unroll
  for (int i = 0; i < 4; ++i)
    #pragma unroll
    for (int j = 0; j < 4; ++j) acc[i][j] = 0.f;

  for (int k0 = 0; k0 < 256; k0 += 64) {
    __syncthreads();
    #pragma unroll
    for (int i = 0; i < 4; ++i) {
      int vi = i*256 + tid;
      int row = vi >> 4, c4 = (vi & 15) << 2;
      *(float4*)&Wt[row][c4] = *(const float4*)&w_proj[(o0+row)*256 + k0 + c4];
    }
    #pragma unroll
    for (int ii = 0; ii < 2; ++ii) {
      int vi = ii*256 + tid;
      int d8 = (vi & 3) << 3;
      int p  = (vi >> 2) & 63;
      int hh2 = vi >> 8;
      int head = (k0 >> 5) + hh2;
      int rr = rbase + (p >> 3), tt = tbase + (p & 7);
      int bhl = b*8 + head;
      uint4 u = *(const uint4*)(ow + (((bhl*64 + rr)*64 + tt)*32 + d8));
      int c = hh2*32 + d8;
      Xt[c+0][p]=bflo(u.x); Xt[c+1][p]=bfhi(u.x);
      Xt[c+2][p]=bflo(u.y); Xt[c+3][p]=bfhi(u.y);
      Xt[c+4][p]=bflo(u.z); Xt[c+5][p]=bfhi(u.z);
      Xt[c+6][p]=bflo(u.w); Xt[c+7][p]=bfhi(u.w);
    }
    __syncthreads();
    gemm_micro(Wt, Xt, to, tp, acc);
  }

  #pragma unroll
  for (int i = 0; i < 4; ++i) {
    int o = o0 + to*4 + i;
    float bias = b_proj[o];
    float4 v = make_float4(acc[i][0]+bias, acc[i][1]+bias, acc[i][2]+bias, acc[i][3]+bias);
    *(float4*)&out[(b*256 + o)*4096 + p0 + tp*4] = v;
  }
}

extern "C" void kernel_launch(void* const* d_in, const int* in_sizes, int n_in,
                              void* d_out, int out_size, void* d_ws, size_t ws_size,
                              hipStream_t stream) {
  (void)in_sizes; (void)n_in; (void)out_size; (void)ws_size;
  const float* x      = (const float*)d_in[0];
  const float* w_qkv  = (const float*)d_in[1];
  const float* b_qkv  = (const float*)d_in[2];
  const float* w_proj = (const float*)d_in[3];
  const float* b_proj = (const float*)d_in[4];
  float* out = (float*)d_out;

  // workspace layout (bf16 window buffers + fp32 routing scratch) ~48.6 MB
  const size_t NB = (size_t)64*64*64*32;          // elems per window buffer
  __hip_bfloat16* qw = (__hip_bfloat16*)d_ws;
  __hip_bfloat16* kw = qw + NB;
  __hip_bfloat16* vw = kw + NB;
  __hip_bfloat16* ow = qw;   // alias: each attn block reads only its own q region
                             // (into regs) before writing its output there.
  float* xmean = (float*)(vw + NB);               // [8][256][64]
  int* topk = (int*)(xmean + (size_t)8*256*64);   // [64][64][4]

  k_qkv  <<<dim3(12, 512), 256, 0, stream>>>(x, w_qkv, b_qkv, qw, kw, vw);
  k_xmean<<<dim3(2048),    256, 0, stream>>>(x, xmean);
  k_route<<<dim3(64),      256, 0, stream>>>(xmean, w_qkv, b_qkv, topk);
  k_attn <<<dim3(4096),    256, 0, stream>>>(qw, kw, vw, topk, ow);
  k_proj <<<dim3(4, 512),  256, 0, stream>>>(ow, w_proj, b_proj, out);
}

// Round 2
// 344.779 us; speedup vs baseline: 2.2374x; 2.2374x over previous
//
#include <hip/hip_runtime.h>
#include <hip/hip_bf16.h>

// B=8, DIM=256, HEADS=8, HD=32, WS=8, TOPK=4, H=W=64, gh=gw=8, R=64, T=64, BH=64.
#define ATT_SCALE 0.17677669529663687f

typedef short v8s __attribute__((ext_vector_type(8)));
typedef float v4f __attribute__((ext_vector_type(4)));
typedef const __attribute__((address_space(1))) unsigned int gu32;
typedef __attribute__((address_space(3))) unsigned int lu32;

__device__ __forceinline__ void g2l16(const void* g, void* l) {
  __builtin_amdgcn_global_load_lds((gu32*)g, (lu32*)l, 16, 0, 0);
}

__device__ __forceinline__ float bflo(unsigned u){ union{unsigned i;float f;}x; x.i=u<<16; return x.f; }
__device__ __forceinline__ float bfhi(unsigned u){ union{unsigned i;float f;}x; x.i=u&0xffff0000u; return x.f; }
__device__ __forceinline__ unsigned short bf16r(float v){
  __hip_bfloat16 h = __float2bfloat16(v);
  return *reinterpret_cast<unsigned short*>(&h);
}
__device__ __forceinline__ unsigned pack_bf2(float a, float b){
  return (unsigned)bf16r(a) | ((unsigned)bf16r(b) << 16);
}

// ---------------- prep: W -> stacked (hi/lo) bf16, transposed-in-K swizzled ----
// Wq[768][768] = [Whi | Wlo | Whi] ; Wp[256][512] = [Whi | Wlo]
// element (m, k') stored at col = (k'&~63) | ((k'&63) ^ ((m&7)<<3))
__global__ __launch_bounds__(256) void prep_w(const float* __restrict__ w_qkv,
                                              const float* __restrict__ w_proj,
                                              unsigned short* __restrict__ Wq,
                                              unsigned short* __restrict__ Wp) {
  const int blk = blockIdx.x, t = threadIdx.x;
  if (blk < 768) {
    const int m = blk;
    float v = w_qkv[m*256 + t];
    __hip_bfloat16 h = __float2bfloat16(v);
    unsigned short hv = *reinterpret_cast<unsigned short*>(&h);
    unsigned short lv = bf16r(v - __bfloat162float(h));
    #pragma unroll
    for (int s = 0; s < 3; ++s) {
      int kp = s*256 + t;
      unsigned short val = (s == 1) ? lv : hv;
      int col = (kp & ~63) | ((kp & 63) ^ ((m & 7) << 3));
      Wq[m*768 + col] = val;
    }
  } else {
    const int m = blk - 768;
    float v = w_proj[m*256 + t];
    __hip_bfloat16 h = __float2bfloat16(v);
    unsigned short hv = *reinterpret_cast<unsigned short*>(&h);
    unsigned short lv = bf16r(v - __bfloat162float(h));
    #pragma unroll
    for (int s = 0; s < 2; ++s) {
      int kp = s*256 + t;
      unsigned short val = (s == 0) ? hv : lv;
      int col = (kp & ~63) | ((kp & 63) ^ ((m & 7) << 3));
      Wp[m*512 + col] = val;
    }
  }
}

// ---------------- prep: X -> Xhi/Xlo [p_global 32768][c 256] bf16, swizzled ----
__global__ __launch_bounds__(256) void prep_x(const float* __restrict__ x,
                                              unsigned short* __restrict__ Xhi,
                                              unsigned short* __restrict__ Xlo) {
  __shared__ __align__(16) char hbuf[8192];
  __shared__ __align__(16) char lbuf[8192];
  const int blk = blockIdx.x;
  const int b = blk >> 8, cc = (blk >> 6) & 3, pc = blk & 63;
  const int c0 = cc << 6, p0 = pc << 6;
  const int t = threadIdx.x, wv = t >> 6, lane = t & 63;

  float hi[16], lo[16];
  const float* xp = x + ((size_t)(b*256 + c0 + wv*16))*4096 + p0 + lane;
  #pragma unroll
  for (int i = 0; i < 16; ++i) {
    float v = xp[(size_t)i*4096];
    __hip_bfloat16 h = __float2bfloat16(v);
    hi[i] = __bfloat162float(h);
    lo[i] = v - hi[i];
  }
  #pragma unroll
  for (int gi = 0; gi < 2; ++gi) {
    uint4 uh, ul;
    uh.x = pack_bf2(hi[gi*8+0], hi[gi*8+1]); uh.y = pack_bf2(hi[gi*8+2], hi[gi*8+3]);
    uh.z = pack_bf2(hi[gi*8+4], hi[gi*8+5]); uh.w = pack_bf2(hi[gi*8+6], hi[gi*8+7]);
    ul.x = pack_bf2(lo[gi*8+0], lo[gi*8+1]); ul.y = pack_bf2(lo[gi*8+2], lo[gi*8+3]);
    ul.z = pack_bf2(lo[gi*8+4], lo[gi*8+5]); ul.w = pack_bf2(lo[gi*8+6], lo[gi*8+7]);
    int off = lane*128 + ((wv*32 + gi*16) ^ ((lane & 7) << 4));
    *(uint4*)(hbuf + off) = uh;
    *(uint4*)(lbuf + off) = ul;
  }
  __syncthreads();
  const size_t rowbase = ((size_t)(b*4096 + p0)) * 512 + (size_t)c0*2;
  #pragma unroll
  for (int s = 0; s < 2; ++s) {
    int gidx = s*256 + t;
    int row = gidx >> 3, gb = (gidx & 7) << 4;
    uint4 vh = *(const uint4*)(hbuf + row*128 + gb);
    uint4 vl = *(const uint4*)(lbuf + row*128 + gb);
    *(uint4*)((char*)Xhi + rowbase + (size_t)row*512 + gb) = vh;
    *(uint4*)((char*)Xlo + rowbase + (size_t)row*512 + gb) = vl;
  }
}

// ---------------- MFMA GEMM: out[M][32768] = Wstack[M][K'] * Xstack[K'][32768] --
// Block: M 256 x N 64, BK=64, K'=KT*64. Wave w owns M rows [w*64, w*64+64).
// EPI 0: qkv -> scatter bf16 to window layout [BH][R][T][HD] + bias
// EPI 1: proj -> fp32 NCHW + bias
template<int KT, int EPI>
__global__ __launch_bounds__(256) void k_gemm(
    const unsigned short* __restrict__ Wstk,
    const unsigned short* __restrict__ B0,
    const unsigned short* __restrict__ B1,
    const float* __restrict__ bias,
    __hip_bfloat16* __restrict__ qbuf, __hip_bfloat16* __restrict__ kbuf,
    __hip_bfloat16* __restrict__ vbuf, float* __restrict__ outp) {
  __shared__ __align__(16) char lds[40960];   // [0,32768): W 256x64, [32768,): X 64x64
  const int tid = threadIdx.x;
  const int wv = tid >> 6, lane = tid & 63;
  const int mt = blockIdx.x, nt = blockIdx.y;
  const size_t wrow = (size_t)KT * 128;       // W row bytes

  v4f acc[4][4];
  #pragma unroll
  for (int i = 0; i < 4; ++i)
    #pragma unroll
    for (int j = 0; j < 4; ++j) acc[i][j] = (v4f){0.f,0.f,0.f,0.f};

  const char* wlanebase = (const char*)Wstk + ((size_t)(mt*256) + (lane>>3))*wrow + (lane&7)*16;
  const size_t prowlane = (size_t)(nt*64 + (lane>>3))*512 + (lane&7)*16;

  for (int kt = 0; kt < KT; ++kt) {
    const unsigned short* bs = (kt < 8) ? B0 : B1;
    const int k0b = ((kt * 64) & 255) * 2;
    __syncthreads();
    #pragma unroll
    for (int o = 0; o < 8; ++o) {             // W tile: 32 KB
      int op = wv*8 + o;
      g2l16(wlanebase + (size_t)(op*8)*wrow + kt*128, lds + op*1024);
    }
    #pragma unroll
    for (int o = 0; o < 2; ++o) {             // X tile: 8 KB
      int op = wv*2 + o;
      g2l16((const char*)bs + prowlane + (size_t)(op*8)*512 + k0b, lds + 32768 + op*1024);
    }
    __syncthreads();
    #pragma unroll
    for (int kk = 0; kk < 2; ++kk) {
      const int kb = kk*64 + ((lane>>4)<<4);
      v8s a[4], b[4];
      #pragma unroll
      for (int i = 0; i < 4; ++i) {
        int mr = wv*64 + i*16 + (lane & 15);
        a[i] = *(const v8s*)(lds + mr*128 + (kb ^ ((mr & 7) << 4)));
      }
      #pragma unroll
      for (int j = 0; j < 4; ++j) {
        int nr = j*16 + (lane & 15);
        b[j] = *(const v8s*)(lds + 32768 + nr*128 + (kb ^ ((nr & 7) << 4)));
      }
      #pragma unroll
      for (int i = 0; i < 4; ++i)
        #pragma unroll
        for (int j = 0; j < 4; ++j)
          acc[i][j] = __builtin_amdgcn_mfma_f32_16x16x32_bf16(a[i], b[j], acc[i][j], 0, 0, 0);
    }
  }

  if (EPI == 0) {
    __hip_bfloat16* outbuf = (mt == 0) ? qbuf : (mt == 1 ? kbuf : vbuf);
    #pragma unroll
    for (int i = 0; i < 4; ++i) {
      int o = mt*256 + wv*64 + i*16 + ((lane >> 4) << 2);
      int head = (o >> 5) & 7, d0 = o & 31;
      float b0 = bias[o], b1 = bias[o+1], b2 = bias[o+2], b3 = bias[o+3];
      #pragma unroll
      for (int j = 0; j < 4; ++j) {
        int p = nt*64 + j*16 + (lane & 15);
        int bb = p >> 12, ploc = p & 4095;
        int h = ploc >> 6, w = ploc & 63;
        int rr = ((h >> 3) << 3) | (w >> 3), tt = ((h & 7) << 3) | (w & 7);
        int bh = bb*8 + head;
        uint2 u;
        u.x = pack_bf2(acc[i][j][0] + b0, acc[i][j][1] + b1);
        u.y = pack_bf2(acc[i][j][2] + b2, acc[i][j][3] + b3);
        *(uint2*)(outbuf + (size_t)(((bh << 6) | rr)*64 + tt)*32 + d0) = u;
      }
    }
  } else {
    #pragma unroll
    for (int i = 0; i < 4; ++i) {
      int o = wv*64 + i*16 + ((lane >> 4) << 2);
      float b0 = bias[o], b1 = bias[o+1], b2 = bias[o+2], b3 = bias[o+3];
      #pragma unroll
      for (int j = 0; j < 4; ++j) {
        int p = nt*64 + j*16 + (lane & 15);
        int bb = p >> 12, ploc = p & 4095;
        float* dst = outp + ((size_t)(bb*256 + o))*4096 + ploc;
        dst[0]     = acc[i][j][0] + b0;
        dst[4096]  = acc[i][j][1] + b1;
        dst[8192]  = acc[i][j][2] + b2;
        dst[12288] = acc[i][j][3] + b3;
      }
    }
  }
}

// ---------------- routing (unchanged from round 1) ---------------------------
__global__ __launch_bounds__(256) void k_xmean(const float* __restrict__ x,
                                               float* __restrict__ xmean) {
  __shared__ float part[64][8];
  const int bc = blockIdx.x;
  const int tid = threadIdx.x;
  const int h = tid >> 2, qq = tid & 3;
  const float* xp = x + (size_t)bc*4096 + h*64 + qq*16;
  float s0 = 0.f, s1 = 0.f;
  #pragma unroll
  for (int j = 0; j < 8; ++j) { s0 += xp[j]; s1 += xp[8+j]; }
  part[h][qq*2]   = s0;
  part[h][qq*2+1] = s1;
  __syncthreads();
  if (tid < 64) {
    int rh = tid >> 3, wc = tid & 7;
    float s = 0.f;
    #pragma unroll
    for (int j = 0; j < 8; ++j) s += part[rh*8+j][wc];
    xmean[bc*64 + tid] = s * (1.0f/64.0f);
  }
}

__global__ __launch_bounds__(256) void k_route(const float* __restrict__ xmean,
                                               const float* __restrict__ w_qkv,
                                               const float* __restrict__ b_qkv,
                                               int* __restrict__ topk) {
  __shared__ float xm[128][64];
  __shared__ float qr[64][33];
  __shared__ float kr[64][33];
  const int bh = blockIdx.x, b = bh >> 3, head = bh & 7;
  const int tid = threadIdx.x;
  const int d = tid & 31, r0 = tid >> 5;
  float qacc[8], kacc[8];
  const float bq = b_qkv[head*32 + d], bk = b_qkv[256 + head*32 + d];
  #pragma unroll
  for (int i = 0; i < 8; ++i) { qacc[i] = bq; kacc[i] = bk; }

  for (int c0 = 0; c0 < 256; c0 += 128) {
    __syncthreads();
    #pragma unroll
    for (int i = 0; i < 32; ++i) {
      int idx = i*256 + tid;
      int row = idx >> 6, col = idx & 63;
      xm[row][col] = xmean[(b*256 + c0 + row)*64 + col];
    }
    __syncthreads();
    const float* wqp = w_qkv + (head*32 + d)*256 + c0;
    const float* wkp = w_qkv + (256 + head*32 + d)*256 + c0;
    for (int c = 0; c < 128; ++c) {
      float wq = wqp[c], wk = wkp[c];
      #pragma unroll
      for (int i = 0; i < 8; ++i) {
        float xv = xm[c][r0 + 8*i];
        qacc[i] += wq * xv;
        kacc[i] += wk * xv;
      }
    }
  }
  #pragma unroll
  for (int i = 0; i < 8; ++i) { qr[r0+8*i][d] = qacc[i]; kr[r0+8*i][d] = kacc[i]; }
  __syncthreads();

  float* ar = &xm[0][0];
  for (int item = tid; item < 4096; item += 256) {
    int i = item >> 6, j = item & 63;
    float s = 0.f;
    #pragma unroll
    for (int dd = 0; dd < 32; ++dd) s += qr[i][dd]*kr[j][dd];
    ar[i*64 + j] = s;
  }
  __syncthreads();
  if (tid < 64) {
    for (int kk = 0; kk < 4; ++kk) {
      float best = -3e38f; int bj = 0;
      for (int j = 0; j < 64; ++j) {
        float v = ar[tid*64 + j];
        if (v > best) { best = v; bj = j; }
      }
      ar[tid*64 + bj] = -3e38f;
      topk[(bh*64 + tid)*4 + kk] = bj;
    }
  }
}

// ---------------- token attention (round 1 + transposed/swizzled output) ------
__global__ __launch_bounds__(256) void k_attn(const __hip_bfloat16* __restrict__ qw,
                                              const __hip_bfloat16* __restrict__ kw,
                                              const __hip_bfloat16* __restrict__ vw,
                                              const int* __restrict__ topk,
                                              unsigned short* __restrict__ owt) {
  __shared__ float ks[64][36];
  __shared__ float vs[64][36];
  const int blk = blockIdx.x;
  const int bh = blk >> 6, rr = blk & 63;
  const int tid = threadIdx.x;
  const int wave = tid >> 6, lane = tid & 63;
  const int tokl = lane & 15, g = lane >> 4;
  const int tok = wave*16 + tokl;

  float qreg[32];
  {
    const uint4* qp4 = (const uint4*)(qw + (size_t)((bh*64 + rr)*64 + tok)*32);
    #pragma unroll
    for (int q = 0; q < 4; ++q) {
      uint4 u = qp4[q];
      qreg[8*q+0]=bflo(u.x); qreg[8*q+1]=bfhi(u.x);
      qreg[8*q+2]=bflo(u.y); qreg[8*q+3]=bfhi(u.y);
      qreg[8*q+4]=bflo(u.z); qreg[8*q+5]=bfhi(u.z);
      qreg[8*q+6]=bflo(u.w); qreg[8*q+7]=bfhi(u.w);
    }
  }
  int idx4[4];
  #pragma unroll
  for (int k2 = 0; k2 < 4; ++k2) idx4[k2] = topk[(bh*64 + rr)*4 + k2];

  float m = -3e38f, ssum = 0.f;
  float o[32];
  #pragma unroll
  for (int dd = 0; dd < 32; ++dd) o[dd] = 0.f;

  for (int win = 0; win < 4; ++win) {
    const int widx = idx4[win];
    __syncthreads();
    {
      const uint4* kp4 = (const uint4*)(kw + (size_t)((bh*64 + widx)*64)*32);
      const uint4* vp4 = (const uint4*)(vw + (size_t)((bh*64 + widx)*64)*32);
      uint4 kv = kp4[tid], vv = vp4[tid];
      int t2 = tid >> 2, d2 = (tid & 3) << 3;
      *(float4*)&ks[t2][d2]   = make_float4(bflo(kv.x),bfhi(kv.x),bflo(kv.y),bfhi(kv.y));
      *(float4*)&ks[t2][d2+4] = make_float4(bflo(kv.z),bfhi(kv.z),bflo(kv.w),bfhi(kv.w));
      *(float4*)&vs[t2][d2]   = make_float4(bflo(vv.x),bfhi(vv.x),bflo(vv.y),bfhi(vv.y));
      *(float4*)&vs[t2][d2+4] = make_float4(bflo(vv.z),bfhi(vv.z),bflo(vv.w),bfhi(vv.w));
    }
    __syncthreads();
    for (int sj = 0; sj < 16; ++sj) {
      const int s = (sj << 2) | g;
      float dot = 0.f;
      #pragma unroll
      for (int q = 0; q < 8; ++q) {
        float4 kv = ((const float4*)&ks[s][0])[q];
        dot += qreg[4*q+0]*kv.x + qreg[4*q+1]*kv.y + qreg[4*q+2]*kv.z + qreg[4*q+3]*kv.w;
      }
      dot *= ATT_SCALE;
      float mnew = fmaxf(m, dot);
      float corr = __expf(m - mnew);
      float p = __expf(dot - mnew);
      ssum = ssum*corr + p;
      #pragma unroll
      for (int q = 0; q < 8; ++q) {
        float4 vv = ((const float4*)&vs[s][0])[q];
        o[4*q+0] = o[4*q+0]*corr + p*vv.x;
        o[4*q+1] = o[4*q+1]*corr + p*vv.y;
        o[4*q+2] = o[4*q+2]*corr + p*vv.z;
        o[4*q+3] = o[4*q+3]*corr + p*vv.w;
      }
      m = mnew;
    }
  }

  #pragma unroll
  for (int mask = 16; mask <= 32; mask <<= 1) {
    float m2 = __shfl_xor(m, mask);
    float s2 = __shfl_xor(ssum, mask);
    float mn = fmaxf(m, m2);
    float c1 = __expf(m - mn), c2 = __expf(m2 - mn);
    ssum = ssum*c1 + s2*c2;
    #pragma unroll
    for (int dd = 0; dd < 32; ++dd) {
      float o2 = __shfl_xor(o[dd], mask);
      o[dd] = o[dd]*c1 + o2*c2;
    }
    m = mn;
  }
  if (g == 0) {
    float inv = 1.0f / ssum;
    int b = bh >> 3, head = bh & 7;
    int h = ((rr >> 3) << 3) | (tok >> 3);
    int w = ((rr & 7) << 3)  | (tok & 7);
    int p_g = (b << 12) | (h << 6) | w;
    unsigned short* rowp = owt + (size_t)p_g*256 + ((head >> 1) << 6);
    int gb = (head & 1) * 4;
    int px = p_g & 7;
    #pragma unroll
    for (int q = 0; q < 4; ++q) {
      uint4 u;
      u.x = pack_bf2(o[8*q+0]*inv, o[8*q+1]*inv);
      u.y = pack_bf2(o[8*q+2]*inv, o[8*q+3]*inv);
      u.z = pack_bf2(o[8*q+4]*inv, o[8*q+5]*inv);
      u.w = pack_bf2(o[8*q+6]*inv, o[8*q+7]*inv);
      *(uint4*)(rowp + (((gb + q) ^ px) << 3)) = u;
    }
  }
}

extern "C" void kernel_launch(void* const* d_in, const int* in_sizes, int n_in,
                              void* d_out, int out_size, void* d_ws, size_t ws_size,
                              hipStream_t stream) {
  (void)in_sizes; (void)n_in; (void)out_size; (void)ws_size;
  const float* x      = (const float*)d_in[0];
  const float* w_qkv  = (const float*)d_in[1];
  const float* b_qkv  = (const float*)d_in[2];
  const float* w_proj = (const float*)d_in[3];
  const float* b_proj = (const float*)d_in[4];
  float* out = (float*)d_out;

  char* ws = (char*)d_ws;
  unsigned short* Xhi = (unsigned short*)ws;                   // 16.8 MB
  unsigned short* Xlo = (unsigned short*)(ws + 16777216);      // 16.8 MB
  unsigned short* Wq  = (unsigned short*)(ws + 33554432);      // 1.18 MB
  unsigned short* Wp  = (unsigned short*)(ws + 34734080);      // 0.26 MB
  __hip_bfloat16* qw  = (__hip_bfloat16*)(ws + 34996224);      // 16.8 MB
  __hip_bfloat16* kw  = (__hip_bfloat16*)(ws + 51773440);      // 16.8 MB
  __hip_bfloat16* vw  = (__hip_bfloat16*)(ws + 68550656);      // 16.8 MB
  float* xmean        = (float*)(ws + 85327872);               // 0.5 MB
  int* topk           = (int*)(ws + 85852160);                 // 64 KB
  unsigned short* owt = Xhi;   // alias: Xhi dead after qkv GEMM; attn rewrites it

  prep_w <<<dim3(1024), 256, 0, stream>>>(w_qkv, w_proj, Wq, Wp);
  prep_x <<<dim3(2048), 256, 0, stream>>>(x, Xhi, Xlo);
  k_xmean<<<dim3(2048), 256, 0, stream>>>(x, xmean);
  k_route<<<dim3(64),   256, 0, stream>>>(xmean, w_qkv, b_qkv, topk);
  k_gemm<12,0><<<dim3(3, 512), 256, 0, stream>>>(Wq, Xhi, Xlo, b_qkv, qw, kw, vw, nullptr);
  k_attn <<<dim3(4096), 256, 0, stream>>>(qw, kw, vw, topk, owt);
  k_gemm<8,1><<<dim3(1, 512), 256, 0, stream>>>(Wp, owt, owt, b_proj, nullptr, nullptr, nullptr, out);
}

// Round 3
// 161.839 us; speedup vs baseline: 4.7665x; 2.1304x over previous
//
#include <hip/hip_runtime.h>
#include <hip/hip_bf16.h>

// B=8, DIM=256, HEADS=8, HD=32, WS=8, TOPK=4, H=W=64, gh=gw=8, R=64, T=64, BH=64.
#define ATT_SCALE 0.17677669529663687f
#define EXP_C1 0.2550349235534668f        // ATT_SCALE * log2(e)
#define EXP_C2 23.083120654223400f        // 16 * log2(e)

typedef short v8s __attribute__((ext_vector_type(8)));
typedef float v4f __attribute__((ext_vector_type(4)));
typedef float v16f __attribute__((ext_vector_type(16)));
typedef const __attribute__((address_space(1))) unsigned int gu32;
typedef __attribute__((address_space(3))) unsigned int lu32;

__device__ __forceinline__ void g2l16(const void* g, void* l) {
  __builtin_amdgcn_global_load_lds((gu32*)g, (lu32*)l, 16, 0, 0);
}

__device__ __forceinline__ float bflo(unsigned u){ union{unsigned i;float f;}x; x.i=u<<16; return x.f; }
__device__ __forceinline__ float bfhi(unsigned u){ union{unsigned i;float f;}x; x.i=u&0xffff0000u; return x.f; }
__device__ __forceinline__ unsigned short bf16r(float v){
  __hip_bfloat16 h = __float2bfloat16(v);
  return *reinterpret_cast<unsigned short*>(&h);
}
__device__ __forceinline__ unsigned pack_bf2(float a, float b){
  return (unsigned)bf16r(a) | ((unsigned)bf16r(b) << 16);
}
__device__ __forceinline__ unsigned cvtpk(float lo, float hi){
  unsigned r;
  asm("v_cvt_pk_bf16_f32 %0, %1, %2" : "=v"(r) : "v"(lo), "v"(hi));
  return r;
}
__device__ __forceinline__ void pl32swap(unsigned &a, unsigned &b){
  asm volatile("v_permlane32_swap_b32 %0, %1" : "+v"(a), "+v"(b));
}

// ---------------- prep: W -> stacked (hi/lo) bf16, transposed-in-K swizzled ----
__global__ __launch_bounds__(256) void prep_w(const float* __restrict__ w_qkv,
                                              const float* __restrict__ w_proj,
                                              unsigned short* __restrict__ Wq,
                                              unsigned short* __restrict__ Wp) {
  const int blk = blockIdx.x, t = threadIdx.x;
  if (blk < 768) {
    const int m = blk;
    float v = w_qkv[m*256 + t];
    __hip_bfloat16 h = __float2bfloat16(v);
    unsigned short hv = *reinterpret_cast<unsigned short*>(&h);
    unsigned short lv = bf16r(v - __bfloat162float(h));
    #pragma unroll
    for (int s = 0; s < 3; ++s) {
      int kp = s*256 + t;
      unsigned short val = (s == 1) ? lv : hv;
      int col = (kp & ~63) | ((kp & 63) ^ ((m & 7) << 3));
      Wq[m*768 + col] = val;
    }
  } else {
    const int m = blk - 768;
    float v = w_proj[m*256 + t];
    __hip_bfloat16 h = __float2bfloat16(v);
    unsigned short hv = *reinterpret_cast<unsigned short*>(&h);
    unsigned short lv = bf16r(v - __bfloat162float(h));
    #pragma unroll
    for (int s = 0; s < 2; ++s) {
      int kp = s*256 + t;
      unsigned short val = (s == 0) ? hv : lv;
      int col = (kp & ~63) | ((kp & 63) ^ ((m & 7) << 3));
      Wp[m*512 + col] = val;
    }
  }
}

// ---------------- prep: X -> Xhi/Xlo [p_global 32768][c 256] bf16, swizzled ----
__global__ __launch_bounds__(256) void prep_x(const float* __restrict__ x,
                                              unsigned short* __restrict__ Xhi,
                                              unsigned short* __restrict__ Xlo) {
  __shared__ __align__(16) char hbuf[8192];
  __shared__ __align__(16) char lbuf[8192];
  const int blk = blockIdx.x;
  const int b = blk >> 8, cc = (blk >> 6) & 3, pc = blk & 63;
  const int c0 = cc << 6, p0 = pc << 6;
  const int t = threadIdx.x, wv = t >> 6, lane = t & 63;

  float hi[16], lo[16];
  const float* xp = x + ((size_t)(b*256 + c0 + wv*16))*4096 + p0 + lane;
  #pragma unroll
  for (int i = 0; i < 16; ++i) {
    float v = xp[(size_t)i*4096];
    __hip_bfloat16 h = __float2bfloat16(v);
    hi[i] = __bfloat162float(h);
    lo[i] = v - hi[i];
  }
  #pragma unroll
  for (int gi = 0; gi < 2; ++gi) {
    uint4 uh, ul;
    uh.x = pack_bf2(hi[gi*8+0], hi[gi*8+1]); uh.y = pack_bf2(hi[gi*8+2], hi[gi*8+3]);
    uh.z = pack_bf2(hi[gi*8+4], hi[gi*8+5]); uh.w = pack_bf2(hi[gi*8+6], hi[gi*8+7]);
    ul.x = pack_bf2(lo[gi*8+0], lo[gi*8+1]); ul.y = pack_bf2(lo[gi*8+2], lo[gi*8+3]);
    ul.z = pack_bf2(lo[gi*8+4], lo[gi*8+5]); ul.w = pack_bf2(lo[gi*8+6], lo[gi*8+7]);
    int off = lane*128 + ((wv*32 + gi*16) ^ ((lane & 7) << 4));
    *(uint4*)(hbuf + off) = uh;
    *(uint4*)(lbuf + off) = ul;
  }
  __syncthreads();
  const size_t rowbase = ((size_t)(b*4096 + p0)) * 512 + (size_t)c0*2;
  #pragma unroll
  for (int s = 0; s < 2; ++s) {
    int gidx = s*256 + t;
    int row = gidx >> 3, gb = (gidx & 7) << 4;
    uint4 vh = *(const uint4*)(hbuf + row*128 + gb);
    uint4 vl = *(const uint4*)(lbuf + row*128 + gb);
    *(uint4*)((char*)Xhi + rowbase + (size_t)row*512 + gb) = vh;
    *(uint4*)((char*)Xlo + rowbase + (size_t)row*512 + gb) = vl;
  }
}

// ---------------- MFMA GEMM (M256 x N64, BK=64) -------------------------------
// EPI 0: qkv -> q/k window layout [BH][R][T][HD]; v TRANSPOSED [BH][R][HD][T]
// EPI 1: proj -> fp32 NCHW + bias
template<int KT, int EPI>
__global__ __launch_bounds__(256) void k_gemm(
    const unsigned short* __restrict__ Wstk,
    const unsigned short* __restrict__ B0,
    const unsigned short* __restrict__ B1,
    const float* __restrict__ bias,
    unsigned short* __restrict__ qbuf, unsigned short* __restrict__ kbuf,
    unsigned short* __restrict__ vbuf, float* __restrict__ outp) {
  __shared__ __align__(16) char lds[40960];
  const int tid = threadIdx.x;
  const int wv = tid >> 6, lane = tid & 63;
  const int mt = blockIdx.x, nt = blockIdx.y;
  const size_t wrow = (size_t)KT * 128;

  v4f acc[4][4];
  #pragma unroll
  for (int i = 0; i < 4; ++i)
    #pragma unroll
    for (int j = 0; j < 4; ++j) acc[i][j] = (v4f){0.f,0.f,0.f,0.f};

  const char* wlanebase = (const char*)Wstk + ((size_t)(mt*256) + (lane>>3))*wrow + (lane&7)*16;
  const size_t prowlane = (size_t)(nt*64 + (lane>>3))*512 + (lane&7)*16;

  for (int kt = 0; kt < KT; ++kt) {
    const unsigned short* bs = (kt < 8) ? B0 : B1;
    const int k0b = ((kt * 64) & 255) * 2;
    __syncthreads();
    #pragma unroll
    for (int o = 0; o < 8; ++o) {
      int op = wv*8 + o;
      g2l16(wlanebase + (size_t)(op*8)*wrow + kt*128, lds + op*1024);
    }
    #pragma unroll
    for (int o = 0; o < 2; ++o) {
      int op = wv*2 + o;
      g2l16((const char*)bs + prowlane + (size_t)(op*8)*512 + k0b, lds + 32768 + op*1024);
    }
    __syncthreads();
    #pragma unroll
    for (int kk = 0; kk < 2; ++kk) {
      const int kb = kk*64 + ((lane>>4)<<4);
      v8s a[4], b[4];
      #pragma unroll
      for (int i = 0; i < 4; ++i) {
        int mr = wv*64 + i*16 + (lane & 15);
        a[i] = *(const v8s*)(lds + mr*128 + (kb ^ ((mr & 7) << 4)));
      }
      #pragma unroll
      for (int j = 0; j < 4; ++j) {
        int nr = j*16 + (lane & 15);
        b[j] = *(const v8s*)(lds + 32768 + nr*128 + (kb ^ ((nr & 7) << 4)));
      }
      #pragma unroll
      for (int i = 0; i < 4; ++i)
        #pragma unroll
        for (int j = 0; j < 4; ++j)
          acc[i][j] = __builtin_amdgcn_mfma_f32_16x16x32_bf16(a[i], b[j], acc[i][j], 0, 0, 0);
    }
  }

  if (EPI == 0) {
    if (mt < 2) {
      unsigned short* outbuf = (mt == 0) ? qbuf : kbuf;
      #pragma unroll
      for (int i = 0; i < 4; ++i) {
        int o = mt*256 + wv*64 + i*16 + ((lane >> 4) << 2);
        int head = (o >> 5) & 7, d0 = o & 31;
        float b0 = bias[o], b1 = bias[o+1], b2 = bias[o+2], b3 = bias[o+3];
        #pragma unroll
        for (int j = 0; j < 4; ++j) {
          int p = nt*64 + j*16 + (lane & 15);
          int bb = p >> 12, ploc = p & 4095;
          int h = ploc >> 6, w = ploc & 63;
          int rr = ((h >> 3) << 3) | (w >> 3), tt = ((h & 7) << 3) | (w & 7);
          int bh = bb*8 + head;
          uint2 u;
          u.x = pack_bf2(acc[i][j][0] + b0, acc[i][j][1] + b1);
          u.y = pack_bf2(acc[i][j][2] + b2, acc[i][j][3] + b3);
          *(uint2*)(outbuf + (size_t)(((bh << 6) | rr)*64 + tt)*32 + d0) = u;
        }
      }
    } else {   // v -> transposed [BH][R][HD 32][T 64]
      #pragma unroll
      for (int i = 0; i < 4; ++i) {
        int o = 512 + wv*64 + i*16 + ((lane >> 4) << 2);
        int vch = o - 512;
        int head = vch >> 5, d0 = vch & 31;
        float bv[4] = {bias[o], bias[o+1], bias[o+2], bias[o+3]};
        #pragma unroll
        for (int j = 0; j < 4; ++j) {
          int p = nt*64 + j*16 + (lane & 15);
          int bb = p >> 12, ploc = p & 4095;
          int h = ploc >> 6, w = ploc & 63;
          int rr = ((h >> 3) << 3) | (w >> 3), tt = ((h & 7) << 3) | (w & 7);
          int bh = bb*8 + head;
          size_t base = ((size_t)((bh << 6) | rr)*32 + d0)*64 + tt;
          #pragma unroll
          for (int c = 0; c < 4; ++c)
            vbuf[base + (size_t)c*64] = bf16r(acc[i][j][c] + bv[c]);
        }
      }
    }
  } else {
    #pragma unroll
    for (int i = 0; i < 4; ++i) {
      int o = wv*64 + i*16 + ((lane >> 4) << 2);
      float b0 = bias[o], b1 = bias[o+1], b2 = bias[o+2], b3 = bias[o+3];
      #pragma unroll
      for (int j = 0; j < 4; ++j) {
        int p = nt*64 + j*16 + (lane & 15);
        int bb = p >> 12, ploc = p & 4095;
        float* dst = outp + ((size_t)(bb*256 + o))*4096 + ploc;
        dst[0]     = acc[i][j][0] + b0;
        dst[4096]  = acc[i][j][1] + b1;
        dst[8192]  = acc[i][j][2] + b2;
        dst[12288] = acc[i][j][3] + b3;
      }
    }
  }
}

// ---------------- routing (unchanged) -----------------------------------------
__global__ __launch_bounds__(256) void k_xmean(const float* __restrict__ x,
                                               float* __restrict__ xmean) {
  __shared__ float part[64][8];
  const int bc = blockIdx.x;
  const int tid = threadIdx.x;
  const int h = tid >> 2, qq = tid & 3;
  const float* xp = x + (size_t)bc*4096 + h*64 + qq*16;
  float s0 = 0.f, s1 = 0.f;
  #pragma unroll
  for (int j = 0; j < 8; ++j) { s0 += xp[j]; s1 += xp[8+j]; }
  part[h][qq*2]   = s0;
  part[h][qq*2+1] = s1;
  __syncthreads();
  if (tid < 64) {
    int rh = tid >> 3, wc = tid & 7;
    float s = 0.f;
    #pragma unroll
    for (int j = 0; j < 8; ++j) s += part[rh*8+j][wc];
    xmean[bc*64 + tid] = s * (1.0f/64.0f);
  }
}

__global__ __launch_bounds__(256) void k_route(const float* __restrict__ xmean,
                                               const float* __restrict__ w_qkv,
                                               const float* __restrict__ b_qkv,
                                               int* __restrict__ topk) {
  __shared__ float xm[128][64];
  __shared__ float qr[64][33];
  __shared__ float kr[64][33];
  const int bh = blockIdx.x, b = bh >> 3, head = bh & 7;
  const int tid = threadIdx.x;
  const int d = tid & 31, r0 = tid >> 5;
  float qacc[8], kacc[8];
  const float bq = b_qkv[head*32 + d], bk = b_qkv[256 + head*32 + d];
  #pragma unroll
  for (int i = 0; i < 8; ++i) { qacc[i] = bq; kacc[i] = bk; }

  for (int c0 = 0; c0 < 256; c0 += 128) {
    __syncthreads();
    #pragma unroll
    for (int i = 0; i < 32; ++i) {
      int idx = i*256 + tid;
      int row = idx >> 6, col = idx & 63;
      xm[row][col] = xmean[(b*256 + c0 + row)*64 + col];
    }
    __syncthreads();
    const float* wqp = w_qkv + (head*32 + d)*256 + c0;
    const float* wkp = w_qkv + (256 + head*32 + d)*256 + c0;
    for (int c = 0; c < 128; ++c) {
      float wq = wqp[c], wk = wkp[c];
      #pragma unroll
      for (int i = 0; i < 8; ++i) {
        float xv = xm[c][r0 + 8*i];
        qacc[i] += wq * xv;
        kacc[i] += wk * xv;
      }
    }
  }
  #pragma unroll
  for (int i = 0; i < 8; ++i) { qr[r0+8*i][d] = qacc[i]; kr[r0+8*i][d] = kacc[i]; }
  __syncthreads();

  float* ar = &xm[0][0];
  for (int item = tid; item < 4096; item += 256) {
    int i = item >> 6, j = item & 63;
    float s = 0.f;
    #pragma unroll
    for (int dd = 0; dd < 32; ++dd) s += qr[i][dd]*kr[j][dd];
    ar[i*64 + j] = s;
  }
  __syncthreads();
  if (tid < 64) {
    for (int kk = 0; kk < 4; ++kk) {
      float best = -3e38f; int bj = 0;
      for (int j = 0; j < 64; ++j) {
        float v = ar[tid*64 + j];
        if (v > best) { best = v; bj = j; }
      }
      ar[tid*64 + bj] = -3e38f;
      topk[(bh*64 + tid)*4 + kk] = bj;
    }
  }
}

// ---------------- MFMA token attention: 1 wave per (bh, region), no LDS -------
// QK^T swapped (S[key][query]); fixed-shift softmax p=exp2(S*C1-C2); P split
// hi+lo bf16; PV via permlane-built A-frags; out -> proj-B layout (swizzled).
__global__ __launch_bounds__(256) void k_attn(const unsigned short* __restrict__ qw,
                                              const unsigned short* __restrict__ kw,
                                              const unsigned short* __restrict__ vwt,
                                              const int* __restrict__ topk,
                                              unsigned short* __restrict__ owt) {
  const int lane = threadIdx.x & 63;
  const int W = blockIdx.x*4 + (threadIdx.x >> 6);
  const int bh = W >> 6, rr = W & 63;
  const int lo5 = lane & 31, hi = lane >> 5;
  const int b = bh >> 3, head = bh & 7;

  // Q fragments (B-operand): lane -> query lo5, channels ck*16 + hi*8 .. +8
  const unsigned short* qb = qw + (size_t)(bh*64 + rr)*2048;
  v8s qf[2][2];
  #pragma unroll
  for (int qt = 0; qt < 2; ++qt)
    #pragma unroll
    for (int ck = 0; ck < 2; ++ck)
      qf[qt][ck] = *(const v8s*)(qb + (qt*32 + lo5)*32 + ck*16 + hi*8);

  int idx4[4];
  #pragma unroll
  for (int w = 0; w < 4; ++w) idx4[w] = topk[(bh*64 + rr)*4 + w];

  v16f O[2];
  #pragma unroll
  for (int qt = 0; qt < 2; ++qt)
    #pragma unroll
    for (int r = 0; r < 16; ++r) O[qt][r] = 0.f;
  float lsum[2] = {0.f, 0.f};

  #pragma unroll
  for (int w = 0; w < 4; ++w) {
    const unsigned short* kb = kw  + (size_t)(bh*64 + idx4[w])*2048;
    const unsigned short* vb = vwt + (size_t)(bh*64 + idx4[w])*2048;
    v8s kf[2][2], vf[4];
    #pragma unroll
    for (int kt = 0; kt < 2; ++kt)
      #pragma unroll
      for (int ck = 0; ck < 2; ++ck)
        kf[kt][ck] = *(const v8s*)(kb + (kt*32 + lo5)*32 + ck*16 + hi*8);
    #pragma unroll
    for (int mk = 0; mk < 4; ++mk)
      vf[mk] = *(const v8s*)(vb + lo5*64 + mk*16 + hi*8);

    v16f S[2][2];
    #pragma unroll
    for (int kt = 0; kt < 2; ++kt)
      #pragma unroll
      for (int qt = 0; qt < 2; ++qt) {
        v16f z;
        #pragma unroll
        for (int r = 0; r < 16; ++r) z[r] = 0.f;
        z = __builtin_amdgcn_mfma_f32_32x32x16_bf16(kf[kt][0], qf[qt][0], z, 0, 0, 0);
        S[kt][qt] = __builtin_amdgcn_mfma_f32_32x32x16_bf16(kf[kt][1], qf[qt][1], z, 0, 0, 0);
      }

    #pragma unroll
    for (int kt = 0; kt < 2; ++kt) {
      #pragma unroll
      for (int qt = 0; qt < 2; ++qt) {
        float p[16];
        #pragma unroll
        for (int r = 0; r < 16; ++r)
          p[r] = __builtin_amdgcn_exp2f(__builtin_fmaf(S[kt][qt][r], EXP_C1, -EXP_C2));
        float s01 = (p[0]+p[1]) + (p[2]+p[3]);
        float s23 = (p[4]+p[5]) + (p[6]+p[7]);
        float s45 = (p[8]+p[9]) + (p[10]+p[11]);
        float s67 = (p[12]+p[13]) + (p[14]+p[15]);
        lsum[qt] += (s01 + s23) + (s45 + s67);

        unsigned wh[8], wl[8];
        #pragma unroll
        for (int i = 0; i < 8; ++i) {
          wh[i] = cvtpk(p[2*i], p[2*i+1]);
          float l0 = p[2*i]   - bflo(wh[i]);
          float l1 = p[2*i+1] - bfhi(wh[i]);
          wl[i] = cvtpk(l0, l1);
        }
        // permlane swaps: (i, i+2) pairs within each half of the 8 words
        pl32swap(wh[0], wh[2]); pl32swap(wh[1], wh[3]);
        pl32swap(wh[4], wh[6]); pl32swap(wh[5], wh[7]);
        pl32swap(wl[0], wl[2]); pl32swap(wl[1], wl[3]);
        pl32swap(wl[4], wl[6]); pl32swap(wl[5], wl[7]);
        union { unsigned u[4]; v8s v; } fA, fB;
        // mk = 2*kt   : words [w0, w1, w2, w3]
        fA.u[0] = wh[0]; fA.u[1] = wh[1]; fA.u[2] = wh[2]; fA.u[3] = wh[3];
        fB.u[0] = wl[0]; fB.u[1] = wl[1]; fB.u[2] = wl[2]; fB.u[3] = wl[3];
        O[qt] = __builtin_amdgcn_mfma_f32_32x32x16_bf16(fA.v, vf[2*kt], O[qt], 0, 0, 0);
        O[qt] = __builtin_amdgcn_mfma_f32_32x32x16_bf16(fB.v, vf[2*kt], O[qt], 0, 0, 0);
        // mk = 2*kt+1 : words [w4, w5, w6, w7]
        fA.u[0] = wh[4]; fA.u[1] = wh[5]; fA.u[2] = wh[6]; fA.u[3] = wh[7];
        fB.u[0] = wl[4]; fB.u[1] = wl[5]; fB.u[2] = wl[6]; fB.u[3] = wl[7];
        O[qt] = __builtin_amdgcn_mfma_f32_32x32x16_bf16(fA.v, vf[2*kt+1], O[qt], 0, 0, 0);
        O[qt] = __builtin_amdgcn_mfma_f32_32x32x16_bf16(fB.v, vf[2*kt+1], O[qt], 0, 0, 0);
      }
    }
  }

  float linv[2];
  #pragma unroll
  for (int qt = 0; qt < 2; ++qt) {
    float t = lsum[qt] + __shfl_xor(lsum[qt], 32);
    linv[qt] = 1.0f / t;
  }

  #pragma unroll
  for (int qt = 0; qt < 2; ++qt) {
    #pragma unroll
    for (int r = 0; r < 16; ++r) {
      int q = (r & 3) + 8*(r >> 2) + 4*hi;          // row within 32-tile
      float li = __shfl(linv[qt], q);
      float val = O[qt][r] * li;
      int tok = qt*32 + q;
      int h = ((rr >> 3) << 3) | (tok >> 3);
      int wcol = ((rr & 7) << 3) | (tok & 7);
      int pg = (b << 12) | (h << 6) | wcol;
      int col = ((head >> 1) << 6) | ((((head & 1) << 5) + lo5) ^ ((tok & 7) << 3));
      owt[(size_t)pg*256 + col] = bf16r(val);
    }
  }
}

extern "C" void kernel_launch(void* const* d_in, const int* in_sizes, int n_in,
                              void* d_out, int out_size, void* d_ws, size_t ws_size,
                              hipStream_t stream) {
  (void)in_sizes; (void)n_in; (void)out_size; (void)ws_size;
  const float* x      = (const float*)d_in[0];
  const float* w_qkv  = (const float*)d_in[1];
  const float* b_qkv  = (const float*)d_in[2];
  const float* w_proj = (const float*)d_in[3];
  const float* b_proj = (const float*)d_in[4];
  float* out = (float*)d_out;

  char* ws = (char*)d_ws;
  unsigned short* Xhi = (unsigned short*)ws;                   // 16.8 MB
  unsigned short* Xlo = (unsigned short*)(ws + 16777216);      // 16.8 MB
  unsigned short* Wq  = (unsigned short*)(ws + 33554432);      // 1.18 MB
  unsigned short* Wp  = (unsigned short*)(ws + 34734080);      // 0.26 MB
  unsigned short* qw  = (unsigned short*)(ws + 34996224);      // 16.8 MB
  unsigned short* kw  = (unsigned short*)(ws + 51773440);      // 16.8 MB
  unsigned short* vwt = (unsigned short*)(ws + 68550656);      // 16.8 MB (transposed)
  float* xmean        = (float*)(ws + 85327872);               // 0.5 MB
  int* topk           = (int*)(ws + 85852160);                 // 64 KB
  unsigned short* owt = Xhi;   // alias: Xhi dead after qkv GEMM

  prep_w <<<dim3(1024), 256, 0, stream>>>(w_qkv, w_proj, Wq, Wp);
  prep_x <<<dim3(2048), 256, 0, stream>>>(x, Xhi, Xlo);
  k_xmean<<<dim3(2048), 256, 0, stream>>>(x, xmean);
  k_route<<<dim3(64),   256, 0, stream>>>(xmean, w_qkv, b_qkv, topk);
  k_gemm<12,0><<<dim3(3, 512), 256, 0, stream>>>(Wq, Xhi, Xlo, b_qkv, qw, kw, vwt, nullptr);
  k_attn <<<dim3(1024), 256, 0, stream>>>(qw, kw, vwt, topk, owt);
  k_gemm<8,1><<<dim3(1, 512), 256, 0, stream>>>(Wp, owt, owt, b_proj, nullptr, nullptr, nullptr, out);
}

// Round 4
// 124.617 us; speedup vs baseline: 6.1902x; 1.2987x over previous
//
#include <hip/hip_runtime.h>
#include <hip/hip_bf16.h>

// B=8, DIM=256, HEADS=8, HD=32, WS=8, TOPK=4, H=W=64, gh=gw=8, R=64, T=64, BH=64.
#define ATT_SCALE 0.17677669529663687f
#define EXP_C1 0.2550349235534668f        // ATT_SCALE * log2(e)
#define EXP_C2 23.083120654223400f        // 16 * log2(e)

typedef short v8s __attribute__((ext_vector_type(8)));
typedef float v4f __attribute__((ext_vector_type(4)));
typedef float v16f __attribute__((ext_vector_type(16)));
typedef const __attribute__((address_space(1))) unsigned int gu32;
typedef __attribute__((address_space(3))) unsigned int lu32;

__device__ __forceinline__ void g2l16(const void* g, void* l) {
  __builtin_amdgcn_global_load_lds((gu32*)g, (lu32*)l, 16, 0, 0);
}

__device__ __forceinline__ float bflo(unsigned u){ union{unsigned i;float f;}x; x.i=u<<16; return x.f; }
__device__ __forceinline__ float bfhi(unsigned u){ union{unsigned i;float f;}x; x.i=u&0xffff0000u; return x.f; }
__device__ __forceinline__ unsigned short bf16r(float v){
  __hip_bfloat16 h = __float2bfloat16(v);
  return *reinterpret_cast<unsigned short*>(&h);
}
__device__ __forceinline__ unsigned pack_bf2(float a, float b){
  return (unsigned)bf16r(a) | ((unsigned)bf16r(b) << 16);
}
__device__ __forceinline__ unsigned cvtpk(float lo, float hi){
  unsigned r;
  asm("v_cvt_pk_bf16_f32 %0, %1, %2" : "=v"(r) : "v"(lo), "v"(hi));
  return r;
}
__device__ __forceinline__ void pl32swap(unsigned &a, unsigned &b){
  asm volatile("v_permlane32_swap_b32 %0, %1" : "+v"(a), "+v"(b));
}

// ---------------- prep: W -> bf16, K-swizzled: col = (k&~63)|((k&63)^((m&7)<<3))
__global__ __launch_bounds__(256) void prep_w(const float* __restrict__ w_qkv,
                                              const float* __restrict__ w_proj,
                                              unsigned short* __restrict__ Wq,
                                              unsigned short* __restrict__ Wp) {
  const int blk = blockIdx.x, t = threadIdx.x;
  const float* src = (blk < 768) ? (w_qkv + blk*256) : (w_proj + (blk-768)*256);
  unsigned short* dst = (blk < 768) ? (Wq + blk*256) : (Wp + (blk-768)*256);
  int col = (t & ~63) | ((t & 63) ^ ((blk & 7) << 3));   // (blk-768)&7 == blk&7
  dst[col] = bf16r(src[t]);
}

// ---------------- prep: X -> [p_global 32768][c 256] bf16, swizzled ------------
__global__ __launch_bounds__(256) void prep_x(const float* __restrict__ x,
                                              unsigned short* __restrict__ Xb) {
  __shared__ __align__(16) char hbuf[8192];
  const int blk = blockIdx.x;
  const int b = blk >> 8, cc = (blk >> 6) & 3, pc = blk & 63;
  const int c0 = cc << 6, p0 = pc << 6;
  const int t = threadIdx.x, wv = t >> 6, lane = t & 63;

  float hi[16];
  const float* xp = x + ((size_t)(b*256 + c0 + wv*16))*4096 + p0 + lane;
  #pragma unroll
  for (int i = 0; i < 16; ++i) hi[i] = xp[(size_t)i*4096];
  #pragma unroll
  for (int gi = 0; gi < 2; ++gi) {
    uint4 uh;
    uh.x = pack_bf2(hi[gi*8+0], hi[gi*8+1]); uh.y = pack_bf2(hi[gi*8+2], hi[gi*8+3]);
    uh.z = pack_bf2(hi[gi*8+4], hi[gi*8+5]); uh.w = pack_bf2(hi[gi*8+6], hi[gi*8+7]);
    int off = lane*128 + ((wv*32 + gi*16) ^ ((lane & 7) << 4));
    *(uint4*)(hbuf + off) = uh;
  }
  __syncthreads();
  const size_t rowbase = ((size_t)(b*4096 + p0)) * 512 + (size_t)c0*2;
  #pragma unroll
  for (int s = 0; s < 2; ++s) {
    int gidx = s*256 + t;
    int row = gidx >> 3, gb = (gidx & 7) << 4;
    uint4 vh = *(const uint4*)(hbuf + row*128 + gb);
    *(uint4*)((char*)Xb + rowbase + (size_t)row*512 + gb) = vh;
  }
}

// ---------------- MFMA GEMM (M256 x N64, BK=64, K=256) ------------------------
// EPI 0: qkv -> q/k window layout [BH][R][T][HD]; v TRANSPOSED [BH][R][HD][T]
// EPI 1: proj -> fp32 NCHW + bias
template<int EPI>
__global__ __launch_bounds__(256) void k_gemm(
    const unsigned short* __restrict__ Wstk,
    const unsigned short* __restrict__ Bmat,
    const float* __restrict__ bias,
    unsigned short* __restrict__ qbuf, unsigned short* __restrict__ kbuf,
    unsigned short* __restrict__ vbuf, float* __restrict__ outp) {
  __shared__ __align__(16) char lds[40960];
  const int tid = threadIdx.x;
  const int wv = tid >> 6, lane = tid & 63;
  const int mt = blockIdx.x, nt = blockIdx.y;

  v4f acc[4][4];
  #pragma unroll
  for (int i = 0; i < 4; ++i)
    #pragma unroll
    for (int j = 0; j < 4; ++j) acc[i][j] = (v4f){0.f,0.f,0.f,0.f};

  const char* wlanebase = (const char*)Wstk + ((size_t)(mt*256) + (lane>>3))*512 + (lane&7)*16;
  const size_t prowlane = (size_t)(nt*64 + (lane>>3))*512 + (lane&7)*16;

  for (int kt = 0; kt < 4; ++kt) {
    const int k0b = kt * 128;
    __syncthreads();
    #pragma unroll
    for (int o = 0; o < 8; ++o) {             // W tile: 32 KB
      int op = wv*8 + o;
      g2l16(wlanebase + (size_t)(op*8)*512 + k0b, lds + op*1024);
    }
    #pragma unroll
    for (int o = 0; o < 2; ++o) {             // X tile: 8 KB
      int op = wv*2 + o;
      g2l16((const char*)Bmat + prowlane + (size_t)(op*8)*512 + k0b, lds + 32768 + op*1024);
    }
    __syncthreads();
    #pragma unroll
    for (int kk = 0; kk < 2; ++kk) {
      const int kb = kk*64 + ((lane>>4)<<4);
      v8s a[4], b[4];
      #pragma unroll
      for (int i = 0; i < 4; ++i) {
        int mr = wv*64 + i*16 + (lane & 15);
        a[i] = *(const v8s*)(lds + mr*128 + (kb ^ ((mr & 7) << 4)));
      }
      #pragma unroll
      for (int j = 0; j < 4; ++j) {
        int nr = j*16 + (lane & 15);
        b[j] = *(const v8s*)(lds + 32768 + nr*128 + (kb ^ ((nr & 7) << 4)));
      }
      #pragma unroll
      for (int i = 0; i < 4; ++i)
        #pragma unroll
        for (int j = 0; j < 4; ++j)
          acc[i][j] = __builtin_amdgcn_mfma_f32_16x16x32_bf16(a[i], b[j], acc[i][j], 0, 0, 0);
    }
  }

  if (EPI == 0) {
    if (mt < 2) {
      unsigned short* outbuf = (mt == 0) ? qbuf : kbuf;
      #pragma unroll
      for (int i = 0; i < 4; ++i) {
        int o = mt*256 + wv*64 + i*16 + ((lane >> 4) << 2);
        int head = (o >> 5) & 7, d0 = o & 31;
        float b0 = bias[o], b1 = bias[o+1], b2 = bias[o+2], b3 = bias[o+3];
        #pragma unroll
        for (int j = 0; j < 4; ++j) {
          int p = nt*64 + j*16 + (lane & 15);
          int bb = p >> 12, ploc = p & 4095;
          int h = ploc >> 6, w = ploc & 63;
          int rr = ((h >> 3) << 3) | (w >> 3), tt = ((h & 7) << 3) | (w & 7);
          int bh = bb*8 + head;
          uint2 u;
          u.x = pack_bf2(acc[i][j][0] + b0, acc[i][j][1] + b1);
          u.y = pack_bf2(acc[i][j][2] + b2, acc[i][j][3] + b3);
          *(uint2*)(outbuf + (size_t)(((bh << 6) | rr)*64 + tt)*32 + d0) = u;
        }
      }
    } else {   // v -> transposed [BH][R][HD 32][T 64]
      #pragma unroll
      for (int i = 0; i < 4; ++i) {
        int o = 512 + wv*64 + i*16 + ((lane >> 4) << 2);
        int vch = o - 512;
        int head = vch >> 5, d0 = vch & 31;
        float bv[4] = {bias[o], bias[o+1], bias[o+2], bias[o+3]};
        #pragma unroll
        for (int j = 0; j < 4; ++j) {
          int p = nt*64 + j*16 + (lane & 15);
          int bb = p >> 12, ploc = p & 4095;
          int h = ploc >> 6, w = ploc & 63;
          int rr = ((h >> 3) << 3) | (w >> 3), tt = ((h & 7) << 3) | (w & 7);
          int bh = bb*8 + head;
          size_t base = ((size_t)((bh << 6) | rr)*32 + d0)*64 + tt;
          #pragma unroll
          for (int c = 0; c < 4; ++c)
            vbuf[base + (size_t)c*64] = bf16r(acc[i][j][c] + bv[c]);
        }
      }
    }
  } else {
    #pragma unroll
    for (int i = 0; i < 4; ++i) {
      int o = wv*64 + i*16 + ((lane >> 4) << 2);
      float b0 = bias[o], b1 = bias[o+1], b2 = bias[o+2], b3 = bias[o+3];
      #pragma unroll
      for (int j = 0; j < 4; ++j) {
        int p = nt*64 + j*16 + (lane & 15);
        int bb = p >> 12, ploc = p & 4095;
        float* dst = outp + ((size_t)(bb*256 + o))*4096 + ploc;
        dst[0]     = acc[i][j][0] + b0;
        dst[4096]  = acc[i][j][1] + b1;
        dst[8192]  = acc[i][j][2] + b2;
        dst[12288] = acc[i][j][3] + b3;
      }
    }
  }
}

// ---------------- routing (unchanged, fully fp32) -----------------------------
__global__ __launch_bounds__(256) void k_xmean(const float* __restrict__ x,
                                               float* __restrict__ xmean) {
  __shared__ float part[64][8];
  const int bc = blockIdx.x;
  const int tid = threadIdx.x;
  const int h = tid >> 2, qq = tid & 3;
  const float* xp = x + (size_t)bc*4096 + h*64 + qq*16;
  float s0 = 0.f, s1 = 0.f;
  #pragma unroll
  for (int j = 0; j < 8; ++j) { s0 += xp[j]; s1 += xp[8+j]; }
  part[h][qq*2]   = s0;
  part[h][qq*2+1] = s1;
  __syncthreads();
  if (tid < 64) {
    int rh = tid >> 3, wc = tid & 7;
    float s = 0.f;
    #pragma unroll
    for (int j = 0; j < 8; ++j) s += part[rh*8+j][wc];
    xmean[bc*64 + tid] = s * (1.0f/64.0f);
  }
}

__global__ __launch_bounds__(256) void k_route(const float* __restrict__ xmean,
                                               const float* __restrict__ w_qkv,
                                               const float* __restrict__ b_qkv,
                                               int* __restrict__ topk) {
  __shared__ float xm[128][64];
  __shared__ float qr[64][33];
  __shared__ float kr[64][33];
  const int bh = blockIdx.x, b = bh >> 3, head = bh & 7;
  const int tid = threadIdx.x;
  const int d = tid & 31, r0 = tid >> 5;
  float qacc[8], kacc[8];
  const float bq = b_qkv[head*32 + d], bk = b_qkv[256 + head*32 + d];
  #pragma unroll
  for (int i = 0; i < 8; ++i) { qacc[i] = bq; kacc[i] = bk; }

  for (int c0 = 0; c0 < 256; c0 += 128) {
    __syncthreads();
    #pragma unroll
    for (int i = 0; i < 32; ++i) {
      int idx = i*256 + tid;
      int row = idx >> 6, col = idx & 63;
      xm[row][col] = xmean[(b*256 + c0 + row)*64 + col];
    }
    __syncthreads();
    const float* wqp = w_qkv + (head*32 + d)*256 + c0;
    const float* wkp = w_qkv + (256 + head*32 + d)*256 + c0;
    for (int c = 0; c < 128; ++c) {
      float wq = wqp[c], wk = wkp[c];
      #pragma unroll
      for (int i = 0; i < 8; ++i) {
        float xv = xm[c][r0 + 8*i];
        qacc[i] += wq * xv;
        kacc[i] += wk * xv;
      }
    }
  }
  #pragma unroll
  for (int i = 0; i < 8; ++i) { qr[r0+8*i][d] = qacc[i]; kr[r0+8*i][d] = kacc[i]; }
  __syncthreads();

  float* ar = &xm[0][0];
  for (int item = tid; item < 4096; item += 256) {
    int i = item >> 6, j = item & 63;
    float s = 0.f;
    #pragma unroll
    for (int dd = 0; dd < 32; ++dd) s += qr[i][dd]*kr[j][dd];
    ar[i*64 + j] = s;
  }
  __syncthreads();
  if (tid < 64) {
    for (int kk = 0; kk < 4; ++kk) {
      float best = -3e38f; int bj = 0;
      for (int j = 0; j < 64; ++j) {
        float v = ar[tid*64 + j];
        if (v > best) { best = v; bj = j; }
      }
      ar[tid*64 + bj] = -3e38f;
      topk[(bh*64 + tid)*4 + kk] = bj;
    }
  }
}

// ---------------- MFMA token attention: 1 wave per (bh, region), no LDS -------
__global__ __launch_bounds__(256) void k_attn(const unsigned short* __restrict__ qw,
                                              const unsigned short* __restrict__ kw,
                                              const unsigned short* __restrict__ vwt,
                                              const int* __restrict__ topk,
                                              unsigned short* __restrict__ owt) {
  const int lane = threadIdx.x & 63;
  const int W = blockIdx.x*4 + (threadIdx.x >> 6);
  const int bh = W >> 6, rr = W & 63;
  const int lo5 = lane & 31, hi = lane >> 5;
  const int b = bh >> 3, head = bh & 7;

  const unsigned short* qb = qw + (size_t)(bh*64 + rr)*2048;
  v8s qf[2][2];
  #pragma unroll
  for (int qt = 0; qt < 2; ++qt)
    #pragma unroll
    for (int ck = 0; ck < 2; ++ck)
      qf[qt][ck] = *(const v8s*)(qb + (qt*32 + lo5)*32 + ck*16 + hi*8);

  int idx4[4];
  #pragma unroll
  for (int w = 0; w < 4; ++w) idx4[w] = topk[(bh*64 + rr)*4 + w];

  v16f O[2];
  #pragma unroll
  for (int qt = 0; qt < 2; ++qt)
    #pragma unroll
    for (int r = 0; r < 16; ++r) O[qt][r] = 0.f;
  float lsum[2] = {0.f, 0.f};

  #pragma unroll
  for (int w = 0; w < 4; ++w) {
    const unsigned short* kb = kw  + (size_t)(bh*64 + idx4[w])*2048;
    const unsigned short* vb = vwt + (size_t)(bh*64 + idx4[w])*2048;
    v8s kf[2][2], vf[4];
    #pragma unroll
    for (int kt = 0; kt < 2; ++kt)
      #pragma unroll
      for (int ck = 0; ck < 2; ++ck)
        kf[kt][ck] = *(const v8s*)(kb + (kt*32 + lo5)*32 + ck*16 + hi*8);
    #pragma unroll
    for (int mk = 0; mk < 4; ++mk)
      vf[mk] = *(const v8s*)(vb + lo5*64 + mk*16 + hi*8);

    v16f S[2][2];
    #pragma unroll
    for (int kt = 0; kt < 2; ++kt)
      #pragma unroll
      for (int qt = 0; qt < 2; ++qt) {
        v16f z;
        #pragma unroll
        for (int r = 0; r < 16; ++r) z[r] = 0.f;
        z = __builtin_amdgcn_mfma_f32_32x32x16_bf16(kf[kt][0], qf[qt][0], z, 0, 0, 0);
        S[kt][qt] = __builtin_amdgcn_mfma_f32_32x32x16_bf16(kf[kt][1], qf[qt][1], z, 0, 0, 0);
      }

    #pragma unroll
    for (int kt = 0; kt < 2; ++kt) {
      #pragma unroll
      for (int qt = 0; qt < 2; ++qt) {
        float p[16];
        #pragma unroll
        for (int r = 0; r < 16; ++r)
          p[r] = __builtin_amdgcn_exp2f(__builtin_fmaf(S[kt][qt][r], EXP_C1, -EXP_C2));
        float s01 = (p[0]+p[1]) + (p[2]+p[3]);
        float s23 = (p[4]+p[5]) + (p[6]+p[7]);
        float s45 = (p[8]+p[9]) + (p[10]+p[11]);
        float s67 = (p[12]+p[13]) + (p[14]+p[15]);
        lsum[qt] += (s01 + s23) + (s45 + s67);

        unsigned wh[8], wl[8];
        #pragma unroll
        for (int i = 0; i < 8; ++i) {
          wh[i] = cvtpk(p[2*i], p[2*i+1]);
          float l0 = p[2*i]   - bflo(wh[i]);
          float l1 = p[2*i+1] - bfhi(wh[i]);
          wl[i] = cvtpk(l0, l1);
        }
        pl32swap(wh[0], wh[2]); pl32swap(wh[1], wh[3]);
        pl32swap(wh[4], wh[6]); pl32swap(wh[5], wh[7]);
        pl32swap(wl[0], wl[2]); pl32swap(wl[1], wl[3]);
        pl32swap(wl[4], wl[6]); pl32swap(wl[5], wl[7]);
        union { unsigned u[4]; v8s v; } fA, fB;
        fA.u[0] = wh[0]; fA.u[1] = wh[1]; fA.u[2] = wh[2]; fA.u[3] = wh[3];
        fB.u[0] = wl[0]; fB.u[1] = wl[1]; fB.u[2] = wl[2]; fB.u[3] = wl[3];
        O[qt] = __builtin_amdgcn_mfma_f32_32x32x16_bf16(fA.v, vf[2*kt], O[qt], 0, 0, 0);
        O[qt] = __builtin_amdgcn_mfma_f32_32x32x16_bf16(fB.v, vf[2*kt], O[qt], 0, 0, 0);
        fA.u[0] = wh[4]; fA.u[1] = wh[5]; fA.u[2] = wh[6]; fA.u[3] = wh[7];
        fB.u[0] = wl[4]; fB.u[1] = wl[5]; fB.u[2] = wl[6]; fB.u[3] = wl[7];
        O[qt] = __builtin_amdgcn_mfma_f32_32x32x16_bf16(fA.v, vf[2*kt+1], O[qt], 0, 0, 0);
        O[qt] = __builtin_amdgcn_mfma_f32_32x32x16_bf16(fB.v, vf[2*kt+1], O[qt], 0, 0, 0);
      }
    }
  }

  float linv[2];
  #pragma unroll
  for (int qt = 0; qt < 2; ++qt) {
    float t = lsum[qt] + __shfl_xor(lsum[qt], 32);
    linv[qt] = 1.0f / t;
  }

  #pragma unroll
  for (int qt = 0; qt < 2; ++qt) {
    #pragma unroll
    for (int r = 0; r < 16; ++r) {
      int q = (r & 3) + 8*(r >> 2) + 4*hi;
      float li = __shfl(linv[qt], q);
      float val = O[qt][r] * li;
      int tok = qt*32 + q;
      int h = ((rr >> 3) << 3) | (tok >> 3);
      int wcol = ((rr & 7) << 3) | (tok & 7);
      int pg = (b << 12) | (h << 6) | wcol;
      int col = ((head >> 1) << 6) | ((((head & 1) << 5) + lo5) ^ ((tok & 7) << 3));
      owt[(size_t)pg*256 + col] = bf16r(val);
    }
  }
}

extern "C" void kernel_launch(void* const* d_in, const int* in_sizes, int n_in,
                              void* d_out, int out_size, void* d_ws, size_t ws_size,
                              hipStream_t stream) {
  (void)in_sizes; (void)n_in; (void)out_size; (void)ws_size;
  const float* x      = (const float*)d_in[0];
  const float* w_qkv  = (const float*)d_in[1];
  const float* b_qkv  = (const float*)d_in[2];
  const float* w_proj = (const float*)d_in[3];
  const float* b_proj = (const float*)d_in[4];
  float* out = (float*)d_out;

  char* ws = (char*)d_ws;
  unsigned short* Xb  = (unsigned short*)ws;                   // 16.78 MB
  unsigned short* Wq  = (unsigned short*)(ws + 16777216);      // 0.39 MB
  unsigned short* Wp  = (unsigned short*)(ws + 17170432);      // 0.13 MB
  unsigned short* qw  = (unsigned short*)(ws + 17301504);      // 16.78 MB
  unsigned short* kw  = (unsigned short*)(ws + 34078720);      // 16.78 MB
  unsigned short* vwt = (unsigned short*)(ws + 50855936);      // 16.78 MB (transposed)
  float* xmean        = (float*)(ws + 67633152);               // 0.52 MB
  int* topk           = (int*)(ws + 68157440);                 // 64 KB
  unsigned short* owt = Xb;    // alias: Xb dead after qkv GEMM

  prep_w <<<dim3(1024), 256, 0, stream>>>(w_qkv, w_proj, Wq, Wp);
  prep_x <<<dim3(2048), 256, 0, stream>>>(x, Xb);
  k_xmean<<<dim3(2048), 256, 0, stream>>>(x, xmean);
  k_route<<<dim3(64),   256, 0, stream>>>(xmean, w_qkv, b_qkv, topk);
  k_gemm<0><<<dim3(3, 512), 256, 0, stream>>>(Wq, Xb, b_qkv, qw, kw, vwt, nullptr);
  k_attn <<<dim3(1024), 256, 0, stream>>>(qw, kw, vwt, topk, owt);
  k_gemm<1><<<dim3(1, 512), 256, 0, stream>>>(Wp, owt, b_proj, nullptr, nullptr, nullptr, out);
}